// Round 10
// baseline (365.894 us; speedup 1.0000x reference)
//
#include <hip/hip_runtime.h>

#pragma clang fp contract(off)

// TV-L1 optical flow inner scale (TVNet), B=8, H=W=480, 5 warps x 5 iters.
// Fused: one kernel per warp step (warp + 5 inner iterations), region 50x40
// = tile 40x30 + halo 5, 512 thr/block, 3 blocks/CU (LDS 48 KB).
// r10: VALU-bound (r9 counters) -> cut instructions, not latency:
//  - interior-block specialization (73% of blocks skip all image-boundary
//    select chains + validity checks; bit-identical arithmetic)
//  - flat LDS indexing (su[idx], neighbors idx+-1 / idx+-RW)
//  - workspace u as float2, p as float4 (1 vector ld/st instead of 2/4)
// All per-pixel fp arithmetic is op-for-op identical to the passing r4-r9
// versions (JAX-f32 linspace, no FMA contraction, left-to-right order).

constexpr int B = 8, H = 480, W = 480;
constexpr int HW = H * W;
constexpr int N = B * HW;

constexpr float THETA = (float)0.3;
constexpr float L_T  = (float)(0.15 * 0.3);   // python f64 product, cast f32
constexpr float TAUT = (float)(0.25 / 0.3);
constexpr float EPSF = (float)1e-12;

#define RW 50              // region width  (incl. halo)
#define RH 40              // region height
#define HALO 5
#define TW 40              // output tile width  (480/12)
#define TH 30              // output tile height (480/16)
#define NTX 12
#define NTY 16
#define TPB 512
#define NPX 4              // ceil(50*40/512); k==3 partial (idx<2000)
#define RPX (RW*RH)        // 2000 region pixels

// WARPK: 0=first (u from input arrays, p=0), 1=mid (ws float2/float4),
//        2=last (write u1/u2/rho outputs, skip final p-phase)
template <int WARPK, bool INTERIOR>
__device__ __forceinline__ void run_body(
    const float* __restrict__ x1, const float* __restrict__ x2,
    const float* __restrict__ u1In, const float* __restrict__ u2In,
    const float2* __restrict__ uIn, const float4* __restrict__ pIn,
    float* __restrict__ u1Out, float* __restrict__ u2Out,
    float2* __restrict__ uOut, float4* __restrict__ pOut,
    float* __restrict__ rhoOut,
    int bx, int by, int b,
    float2* __restrict__ su, float2* __restrict__ spA,
    float2* __restrict__ spB)
{
  const int ox = bx * TW - HALO;
  const int oy = by * TH - HALO;
  const int tid = threadIdx.x;
  const int base = b * HW;
  const float* __restrict__ im = x2 + base;

  float cdx[NPX], cdy[NPX], crc[NPX];   // dxw, dyw, rho_c (only reg state)
  int lxA[NPX], lyA[NPX];
#pragma unroll
  for (int k = 0; k < NPX; ++k) {
    int idx = tid + k * TPB;
    lyA[k] = idx / RW;
    lxA[k] = idx - lyA[k] * RW;
  }

  // ---- warp stage: bilinear warp of x2 & its centered gradients ----
#pragma unroll
  for (int k = 0; k < NPX; ++k) {
    int idx = tid + k * TPB;
    if (idx < RPX) {
      int lx = lxA[k], ly = lyA[k];
      int px = ox + lx, py = oy + ly;
      bool valid = INTERIOR ? true : (px >= 0 && px < W && py >= 0 && py < H);
      if (valid) {
        int gi = base + py * W + px;
        float u, v;
        if (WARPK == 0) { u = u1In[gi]; v = u2In[gi]; }
        else            { float2 uv = uIn[gi]; u = uv.x; v = uv.y; }
        // JAX f32 linspace: delta = 2/479 (f32 div), out = -1 + i*delta
        const float step = 2.0f / 479.0f;
        float gx = -1.0f + (float)px * step;
        float gy = -1.0f + (float)py * step;
        float X = ((gx + u * (float)(2.0 / 480.0)) + 1.0f) * 240.0f;
        float Y = ((gy + v * (float)(2.0 / 480.0)) + 1.0f) * 240.0f;
        float fX = floorf(X), fY = floorf(Y);
        int ix = (int)fX, iy = (int)fY;
        int x0i = min(max(ix, 0), W - 1);
        int x1i = min(max(ix + 1, 0), W - 1);
        int y0i = min(max(iy, 0), H - 1);
        int y1i = min(max(iy + 1, 0), H - 1);
        float x0f = (float)x0i, x1f = (float)x1i;
        float y0f = (float)y0i, y1f = (float)y1i;
        float wa = (x1f - X) * (y1f - Y);
        float wb = (x1f - X) * (Y - y0f);
        float wc = (X - x0f) * (y1f - Y);
        float wd = (X - x0f) * (Y - y0f);
        auto at = [&](int yy, int xx) -> float { return im[yy * W + xx]; };
        auto dxc = [&](int yy, int xx) -> float {
          int xm = max(xx - 1, 0), xp = min(xx + 1, W - 1);
          return 0.5f * (at(yy, xp) - at(yy, xm));
        };
        auto dyc = [&](int yy, int xx) -> float {
          int ym = max(yy - 1, 0), yp = min(yy + 1, H - 1);
          return 0.5f * (at(yp, xx) - at(ym, xx));
        };
        float x2w = ((wa * at(y0i, x0i) + wb * at(y1i, x0i)) + wc * at(y0i, x1i)) + wd * at(y1i, x1i);
        float dxw = ((wa * dxc(y0i, x0i) + wb * dxc(y1i, x0i)) + wc * dxc(y0i, x1i)) + wd * dxc(y1i, x1i);
        float dyw = ((wa * dyc(y0i, x0i) + wb * dyc(y1i, x0i)) + wc * dyc(y0i, x1i)) + wd * dyc(y1i, x1i);
        cdx[k] = dxw; cdy[k] = dyw;
        crc[k] = ((x2w - dxw * u) - dyw * v) - x1[gi];
        float4 q;
        if (WARPK == 0) q = make_float4(0.f, 0.f, 0.f, 0.f);
        else            q = pIn[gi];            // {p11,p12,p21,p22}
        su[idx]  = make_float2(u, v);
        spA[idx] = make_float2(q.x, q.z);       // {p11,p21}
        spB[idx] = make_float2(q.y, q.w);       // {p12,p22}
      }
    }
  }
  __syncthreads();

  // ---- 5 inner iterations ----
  for (int t = 1; t <= 5; ++t) {
    int ulox, uloy, uhix, uhiy;
    if (INTERIOR) {
      ulox = ox + t; uloy = oy + t;
      uhix = ox + RW + 1 - t; uhiy = oy + RH + 1 - t;
    } else {
      ulox = ox + t; if (ulox < 0) ulox = 0;
      uloy = oy + t; if (uloy < 0) uloy = 0;
      uhix = (ox + RW >= W) ? W : (ox + RW + 1 - t);
      uhiy = (oy + RH >= H) ? H : (oy + RH + 1 - t);
    }

    // u-phase: reads own u/p + left/up p pairs (LDS), writes u (LDS)
#pragma unroll
    for (int k = 0; k < NPX; ++k) {
      int idx = tid + k * TPB;
      if (idx < RPX) {
        int lx = lxA[k], ly = lyA[k];
        int px = ox + lx, py = oy + ly;
        if (px >= ulox && px < uhix && py >= uloy && py < uhiy) {
          float2 uo  = su[idx];
          float2 pAo = spA[idx];        // {p11, p21} own
          float2 pBo = spB[idx];        // {p12, p22} own
          float2 pl = spA[idx - 1];     // {p11, p21} left
          float2 pu = spB[idx - RW];    // {p12, p22} up
          float dx = cdx[k], dy = cdy[k];
          float u = uo.x, v = uo.y;
          float rho = ((crc[k] + dx * u) + dy * v) + EPSF;
          float grad = (dx * dx + dy * dy) + EPSF;
          float lt_g = L_T * grad;
          float s;
          if (rho < -lt_g)      s = L_T;
          else if (rho > lt_g)  s = -L_T;
          else if (grad > EPSF) s = (-rho) / grad;
          else                  s = 0.f;
          float v1 = s * dx + u;
          float v2 = s * dy + v;
          float dvx1, dvy1, dvx2, dvy2;
          if (INTERIOR) {
            dvx1 = pAo.x - pl.x;
            dvy1 = pBo.x - pu.x;
            dvx2 = pAo.y - pl.y;
            dvy2 = pBo.y - pu.y;
          } else {
            if (px == 0)          dvx1 = pAo.x;
            else if (px == W - 1) dvx1 = -pl.x;
            else                  dvx1 = pAo.x - pl.x;
            if (py == 0)          dvy1 = pBo.x;
            else if (py == H - 1) dvy1 = -pu.x;
            else                  dvy1 = pBo.x - pu.x;
            if (px == 0)          dvx2 = pAo.y;
            else if (px == W - 1) dvx2 = -pl.y;
            else                  dvx2 = pAo.y - pl.y;
            if (py == 0)          dvy2 = pBo.y;
            else if (py == H - 1) dvy2 = -pu.y;
            else                  dvy2 = pBo.y - pu.y;
          }
          float nu1 = v1 + THETA * (dvx1 + dvy1);
          float nu2 = v2 + THETA * (dvx2 + dvy2);
          su[idx] = make_float2(nu1, nu2);
          if (WARPK == 2 && t == 5) {
            if (lx >= HALO && lx < HALO + TW && ly >= HALO && ly < HALO + TH)
              rhoOut[base + py * W + px] = rho;
          }
        }
      }
    }
    __syncthreads();

    // p-phase: reads own/right/down u + own p (LDS), writes p (LDS).
    // Skipped on the last warp's final iteration (p^5 is dead there).
    if (!(WARPK == 2 && t == 5)) {
      int phix, phiy;
      if (INTERIOR) { phix = ox + RW - t; phiy = oy + RH - t; }
      else {
        phix = (ox + RW >= W) ? W : (ox + RW - t);
        phiy = (oy + RH >= H) ? H : (oy + RH - t);
      }
#pragma unroll
      for (int k = 0; k < NPX; ++k) {
        int idx = tid + k * TPB;
        if (idx < RPX) {
          int lx = lxA[k], ly = lyA[k];
          int px = ox + lx, py = oy + ly;
          if (px >= ulox && px < phix && py >= uloy && py < phiy) {
            float2 uo = su[idx];
            float2 uR = su[idx + 1];     // unused when px==W-1 (pad-safe)
            float2 uD = su[idx + RW];    // unused when py==H-1
            float2 pAo = spA[idx];
            float2 pBo = spB[idx];
            float u1c = uo.x, u2c = uo.y;
            float u1x, u1y, u2x, u2y;
            if (INTERIOR) {
              u1x = uR.x - u1c; u1y = uD.x - u1c;
              u2x = uR.y - u2c; u2y = uD.y - u2c;
            } else {
              u1x = (px < W - 1) ? uR.x - u1c : 0.f;
              u1y = (py < H - 1) ? uD.x - u1c : 0.f;
              u2x = (px < W - 1) ? uR.y - u2c : 0.f;
              u2y = (py < H - 1) ? uD.y - u2c : 0.f;
            }
            float n1 = 1.0f + TAUT * sqrtf((u1x * u1x + u1y * u1y) + EPSF);
            float n2 = 1.0f + TAUT * sqrtf((u2x * u2x + u2y * u2y) + EPSF);
            float np11 = (pAo.x + TAUT * u1x) / n1;
            float np12 = (pBo.x + TAUT * u1y) / n1;
            float np21 = (pAo.y + TAUT * u2x) / n2;
            float np22 = (pBo.y + TAUT * u2y) / n2;
            spA[idx] = make_float2(np11, np21);
            spB[idx] = make_float2(np12, np22);
          }
        }
      }
    }
    __syncthreads();
  }

  // ---- write-out: tile pixels only (local coords: lx in [5,45), ly in [5,35)) ----
#pragma unroll
  for (int k = 0; k < NPX; ++k) {
    int idx = tid + k * TPB;
    if (idx < RPX) {
      int lx = lxA[k], ly = lyA[k];
      if (lx >= HALO && lx < HALO + TW && ly >= HALO && ly < HALO + TH) {
        int gi = base + (oy + ly) * W + (ox + lx);
        float2 uo = su[idx];
        if (WARPK == 2) {
          u1Out[gi] = uo.x;
          u2Out[gi] = uo.y;
        } else {
          uOut[gi] = uo;
          float2 a = spA[idx], c = spB[idx];
          pOut[gi] = make_float4(a.x, c.x, a.y, c.y);  // {p11,p12,p21,p22}
        }
      }
    }
  }
}

template <int WARPK>
__global__ __launch_bounds__(TPB, 4) void k_fused(
    const float* __restrict__ x1, const float* __restrict__ x2,
    const float* __restrict__ u1In, const float* __restrict__ u2In,
    const float2* __restrict__ uIn, const float4* __restrict__ pIn,
    float* __restrict__ u1Out, float* __restrict__ u2Out,
    float2* __restrict__ uOut, float4* __restrict__ pOut,
    float* __restrict__ rhoOut)
{
  __shared__ float2 su[RPX], spA[RPX], spB[RPX];
  int blk = blockIdx.x;
  int bx = blk % NTX;
  int by = (blk / NTX) % NTY;
  int b  = blk / (NTX * NTY);
  bool interior = (bx > 0 && bx < NTX - 1 && by > 0 && by < NTY - 1);
  if (interior)
    run_body<WARPK, true >(x1, x2, u1In, u2In, uIn, pIn, u1Out, u2Out,
                           uOut, pOut, rhoOut, bx, by, b, su, spA, spB);
  else
    run_body<WARPK, false>(x1, x2, u1In, u2In, uIn, pIn, u1Out, u2Out,
                           uOut, pOut, rhoOut, bx, by, b, su, spA, spB);
}

extern "C" void kernel_launch(void* const* d_in, const int* in_sizes, int n_in,
                              void* d_out, int out_size, void* d_ws, size_t ws_size,
                              hipStream_t stream) {
  const float* x1 = (const float*)d_in[0];
  const float* x2 = (const float*)d_in[1];
  const float* u1_in = (const float*)d_in[2];
  const float* u2_in = (const float*)d_in[3];

  float* u1o  = (float*)d_out;
  float* u2o  = u1o + (size_t)N;
  float* rhoo = u1o + (size_t)2 * N;

  float* ws  = (float*)d_ws;
  float2* uA = (float2*)ws;                       // 2N floats
  float4* pA = (float4*)(ws + (size_t)2 * N);     // 4N floats (16B aligned)
  float2* uB = (float2*)(ws + (size_t)6 * N);     // 2N floats
  float4* pB = (float4*)(ws + (size_t)8 * N);     // 4N floats (16B aligned)

  dim3 grd(NTX * NTY * B), blk(TPB);
  k_fused<0><<<grd, blk, 0, stream>>>(x1, x2, u1_in, u2_in, nullptr, nullptr,
                                      nullptr, nullptr, uA, pA, rhoo);
  k_fused<1><<<grd, blk, 0, stream>>>(x1, x2, nullptr, nullptr, uA, pA,
                                      nullptr, nullptr, uB, pB, rhoo);
  k_fused<1><<<grd, blk, 0, stream>>>(x1, x2, nullptr, nullptr, uB, pB,
                                      nullptr, nullptr, uA, pA, rhoo);
  k_fused<1><<<grd, blk, 0, stream>>>(x1, x2, nullptr, nullptr, uA, pA,
                                      nullptr, nullptr, uB, pB, rhoo);
  k_fused<2><<<grd, blk, 0, stream>>>(x1, x2, nullptr, nullptr, uB, pB,
                                      u1o, u2o, nullptr, nullptr, rhoo);
}